// Round 22
// baseline (37.954 us; speedup 1.0000x reference)
//
#include <hip/hip_runtime.h>
#include <math.h>

#define BB 4
#define CC 64
#define OO 64
#define HH 128
#define WW 128
#define HWsz (HH * WW)

typedef __attribute__((ext_vector_type(8))) _Float16 half8;
typedef __attribute__((ext_vector_type(4))) float floatx4;

static __device__ __forceinline__ float h2f(unsigned u) {
    union { unsigned short s; _Float16 h; } v;
    v.s = (unsigned short)u;
    return (float)v.h;
}

// ---------------------------------------------------------------------------
// pre: (blocks 0..511)  x NCHW f32 -> xh merged NHWC f16 (px = 128B = 1 line)
//      (blocks 512..727) fragment-ordered f16 weight repack:
//  waf[((k*2+kh)*4+m)*512 + lane*8 + j], wcf[((k*2+kh)*2+m)*512 + lane*8 + j]
//  (waf and wcf CONTIGUOUS in ws -> fused kernel stages both in one copy)
// ---------------------------------------------------------------------------
__global__ __launch_bounds__(256) void pre_kernel(
    const float* __restrict__ x, const float* __restrict__ wgt,
    const float* __restrict__ ow, const float* __restrict__ mw,
    _Float16* __restrict__ xh, _Float16* __restrict__ waf,
    _Float16* __restrict__ wcf)
{
    int bid = blockIdx.x;
    int tid = threadIdx.x;
    if (bid < 512) {
        int b = bid >> 7, y = bid & 127;
        int px = tid & 127;
        int ch = (tid >> 7) * 32;
        const float* xp = x + (size_t)(b * CC + ch) * HWsz + y * WW + px;
        _Float16 buf[32];
#pragma unroll
        for (int q = 0; q < 32; ++q)
            buf[q] = (_Float16)xp[(size_t)q * HWsz];
        _Float16* dst = xh + ((size_t)(b * HH + y) * WW + px) * 64 + ch;
#pragma unroll
        for (int q = 0; q < 4; ++q)
            *(half8*)&dst[q * 8] = *(const half8*)&buf[q * 8];
    } else {
        int i = (bid - 512) * 256 + tid;
        if (i < 36864) {
            int j = i & 7, lane = (i >> 3) & 63, rest = i >> 9;
            int m = rest & 3, kh = (rest >> 2) & 1, k = rest >> 3;
            int o = m * 16 + (lane & 15);
            int c = kh * 32 + ((lane >> 4) << 3) + j;
            waf[i] = (_Float16)wgt[o * 576 + c * 9 + k];
        } else if (i < 55296) {
            int t = i - 36864;
            int j = t & 7, lane = (t >> 3) & 63, rest = t >> 9;
            int m = rest & 1, kh = (rest >> 1) & 1, k = rest >> 2;
            int o = m * 16 + (lane & 15);
            int c = kh * 32 + ((lane >> 4) << 3) + j;
            float v = 0.f;
            if (o < 18) v = ow[o * 576 + c * 9 + k];
            else if (o < 27) v = mw[(o - 18) * 576 + c * 9 + k];
            wcf[t] = (_Float16)v;
        }
    }
}

// ---------------------------------------------------------------------------
// fused kernel (fp16): all weights in LDS, full-line loads, TAP-PAIR BATCHED
// phase-2 gathers (MLP depth 2), packed om params.
// 256 blocks x 1024 thr = 1 block/CU; 16 waves = 4 rows x 4 strips x 64-px
// column half. LDS pool 161280 B; bounce2 overlays wcf (dead after phase 1).
// ---------------------------------------------------------------------------
__global__ __launch_bounds__(1024, 1) void fused_kernel(
    const _Float16* __restrict__ wsrc, const _Float16* __restrict__ xh,
    const float* __restrict__ ob, const float* __restrict__ mb,
    float* __restrict__ out)
{
    __shared__ __align__(16) _Float16 pool[80640];   // 161280 B
    // layout (halfs): waf [0,36864) | wcf [36864,55296) | omyx [55296,59904)
    //                 | omm [59904,62208) | bounce1 [62208,80640)
    //                 bounce2 overlays wcf: [36864, 36864+16384)

    int tid = threadIdx.x;
    int gid = blockIdx.x;
    // XCD swizzle: 256 blocks = 8 XCDs x 32 contiguous region-tiles
    int sid = (gid & 7) * 32 + (gid >> 3);
    int b = sid >> 6;
    int t = sid & 63;
    int rq = t >> 1;
    int q = t & 1;

    int wv = tid >> 6;         // 0..15
    int lane = tid & 63;
    int s = wv & 3;            // strip
    int h = rq * 4 + (wv >> 2);
    int p0 = q << 6;
    int g = lane >> 4;
    int pl = lane & 15;
    int oct = lane & 7;        // full-line role: channel octet
    int pxg = lane >> 3;       // full-line role: pixel within 8-px group

    const _Float16* xhb = xh + ((size_t)b << 20);
    _Float16* omyx = pool + 55296;
    _Float16* omm  = pool + 59904;
    _Float16* bb1  = pool + 62208 + wv * 1152;
    _Float16* bb2  = pool + 36864 + wv * 1024;

    // ---- cooperative weight stage: 55296 halfs = 6912 chunks of 16B -------
#pragma unroll
    for (int it = 0; it < 7; ++it) {
        int c = it * 1024 + tid;
        if (c < 6912)
            *(half8*)&pool[c * 8] = *(const half8*)(wsrc + c * 8);
    }
    __syncthreads();

    // ---------------- phase 1: conv via full-line row staging --------------
    floatx4 accC0 = {0.f, 0.f, 0.f, 0.f};
    floatx4 accC1 = {0.f, 0.f, 0.f, 0.f};

#define STAGE_ROW(KY) do {                                                   \
    int gy = h + (KY) - 1;                                                   \
    half8 z = {0, 0, 0, 0, 0, 0, 0, 0};                                      \
    _Pragma("unroll") for (int j = 0; j < 3; ++j) {                          \
        int pxi = j * 8 + pxg;                                               \
        bool act = (j < 2) | (pxg < 2);                                      \
        int col = p0 + s * 16 - 1 + pxi;                                     \
        bool val = act & (gy >= 0) & (gy < HH) & (col >= 0) & (col < WW);    \
        half8 v = z;                                                         \
        if (val)                                                             \
            v = *(const half8*)(xhb + (((size_t)gy * WW + col) << 6) + oct * 8); \
        if (act)                                                             \
            *(half8*)&bb1[(pxi << 6) + ((oct ^ (pxi & 7)) << 3)] = v;        \
    }                                                                        \
} while (0)

#define CONVT(KY, KX) do {                                                   \
    int K = (KY) * 3 + (KX);                                                 \
    int pc = pl + (KX);                                                      \
    half8 a0 = *(const half8*)&bb1[(pc << 6) + ((g ^ (pc & 7)) << 3)];       \
    half8 a1 = *(const half8*)&bb1[(pc << 6) + (((g + 4) ^ (pc & 7)) << 3)]; \
    const _Float16* wp = &pool[36864 + (K << 11) + lane * 8];                \
    half8 w00 = *(const half8*)(wp + (0 << 9));                              \
    half8 w01 = *(const half8*)(wp + (1 << 9));                              \
    half8 w10 = *(const half8*)(wp + (2 << 9));                              \
    half8 w11 = *(const half8*)(wp + (3 << 9));                              \
    accC0 = __builtin_amdgcn_mfma_f32_16x16x32_f16(w00, a0, accC0, 0, 0, 0); \
    accC1 = __builtin_amdgcn_mfma_f32_16x16x32_f16(w01, a0, accC1, 0, 0, 0); \
    accC0 = __builtin_amdgcn_mfma_f32_16x16x32_f16(w10, a1, accC0, 0, 0, 0); \
    accC1 = __builtin_amdgcn_mfma_f32_16x16x32_f16(w11, a1, accC1, 0, 0, 0); \
} while (0)

    STAGE_ROW(0); CONVT(0, 0); CONVT(0, 1); CONVT(0, 2);
    STAGE_ROW(1); CONVT(1, 0); CONVT(1, 1); CONVT(1, 2);
    STAGE_ROW(2); CONVT(2, 0); CONVT(2, 1); CONVT(2, 2);

    // om epilogue (packed: omyx[(px9+tap)*2+{0,1}] = oy,ox; omm[px9+tap] = mk)
    {
        int pxbase = ((wv << 4) + pl) * 9;
#pragma unroll
        for (int j = 0; j < 4; ++j) {
            int o = g * 4 + j;
            omyx[(pxbase + (o >> 1)) * 2 + (o & 1)] = (_Float16)(accC0[j] + ob[o]);
            int o2 = 16 + g * 4 + j;
            float v = accC1[j];
            if (o2 < 18)
                omyx[(pxbase + (o2 >> 1)) * 2 + (o2 & 1)] = (_Float16)(v + ob[o2]);
            else if (o2 < 27)
                omm[pxbase + (o2 - 18)] =
                    (_Float16)(1.0f / (1.0f + expf(-(v + mb[o2 - 18]))));
        }
    }
    // barrier: all waves must finish reading wcf before bb2 (overlay) writes
    __syncthreads();

    // ---------------- phase 2: tap-pair batched gathers + GEMM -------------
    floatx4 acc0 = {0.f, 0.f, 0.f, 0.f}, acc1 = {0.f, 0.f, 0.f, 0.f};
    floatx4 acc2 = {0.f, 0.f, 0.f, 0.f}, acc3 = {0.f, 0.f, 0.f, 0.f};

    int pbA = ((wv << 4) + pxg) * 9;        // om base, pixel role A
    int pbB = ((wv << 4) + 8 + pxg) * 9;    // om base, pixel role B

#define MKP(K, PB, PX, U00, U01, U10, U11, I00, I01, I10, I11) do {          \
    int ky = (K) / 3, kx = (K) - ky * 3;                                     \
    unsigned pk_ = *(const unsigned*)&omyx[((PB) + (K)) * 2];                \
    float oy = h2f(pk_ & 0xffffu);                                           \
    float ox = h2f(pk_ >> 16);                                               \
    float mk = (float)omm[(PB) + (K)];                                       \
    float py = oy + (float)(h + ky - 1);                                     \
    float qx = ox + (float)(p0 + s * 16 + (PX) + kx - 1);                    \
    float y0f = floorf(py), x0f = floorf(qx);                                \
    float dyy = py - y0f, dxx = qx - x0f;                                    \
    int y0 = (int)y0f, x0 = (int)x0f;                                        \
    int y1 = y0 + 1, x1 = x0 + 1;                                            \
    bool vy0 = (y0 >= 0) & (y0 < HH), vy1 = (y1 >= 0) & (y1 < HH);           \
    bool vx0 = (x0 >= 0) & (x0 < WW), vx1 = (x1 >= 0) & (x1 < WW);           \
    U00 = (vy0 & vx0) ? (1.f - dyy) * (1.f - dxx) * mk : 0.f;                \
    U01 = (vy0 & vx1) ? (1.f - dyy) * dxx * mk : 0.f;                        \
    U10 = (vy1 & vx0) ? dyy * (1.f - dxx) * mk : 0.f;                        \
    U11 = (vy1 & vx1) ? dyy * dxx * mk : 0.f;                                \
    int yc0 = min(max(y0, 0), HH - 1), yc1 = min(max(y1, 0), HH - 1);        \
    int xc0 = min(max(x0, 0), WW - 1), xc1 = min(max(x1, 0), WW - 1);        \
    I00 = ((yc0 * WW + xc0) << 6) + oct * 8;                                 \
    I01 = ((yc0 * WW + xc1) << 6) + oct * 8;                                 \
    I10 = ((yc1 * WW + xc0) << 6) + oct * 8;                                 \
    I11 = ((yc1 * WW + xc1) << 6) + oct * 8;                                 \
} while (0)

#define SPLAT8(H) ((half8){(H), (H), (H), (H), (H), (H), (H), (H)})
#define MF(Q, B, A) A = __builtin_amdgcn_mfma_f32_16x16x32_f16(Q, B, A, 0, 0, 0)

// process one tap's blended data through bounce buffer BB + weights + MFMA
#define PROC(K, BB, A0, A1, A2, A3, E0, E1, E2, E3,                          \
             U0, U1, U2, U3, V0, V1, V2, V3) do {                            \
    half8 bfA = A0 * SPLAT8((_Float16)U0);                                   \
    bfA = bfA + A1 * SPLAT8((_Float16)U1);                                   \
    bfA = bfA + A2 * SPLAT8((_Float16)U2);                                   \
    bfA = bfA + A3 * SPLAT8((_Float16)U3);                                   \
    half8 bfB = E0 * SPLAT8((_Float16)V0);                                   \
    bfB = bfB + E1 * SPLAT8((_Float16)V1);                                   \
    bfB = bfB + E2 * SPLAT8((_Float16)V2);                                   \
    bfB = bfB + E3 * SPLAT8((_Float16)V3);                                   \
    *(half8*)&(BB)[(pxg << 6) + ((oct ^ pxg) << 3)] = bfA;                   \
    *(half8*)&(BB)[((8 + pxg) << 6) + ((oct ^ pxg) << 3)] = bfB;             \
    half8 bf = *(const half8*)&(BB)[(pl << 6) + ((g ^ (pl & 7)) << 3)];      \
    half8 bd = *(const half8*)&(BB)[(pl << 6) + (((g + 4) ^ (pl & 7)) << 3)];\
    const _Float16* wk = &pool[((K) << 12) + lane * 8];                      \
    half8 q0 = *(const half8*)(wk + (0 << 9));                               \
    half8 q1 = *(const half8*)(wk + (1 << 9));                               \
    half8 q2 = *(const half8*)(wk + (2 << 9));                               \
    half8 q3 = *(const half8*)(wk + (3 << 9));                               \
    half8 q4 = *(const half8*)(wk + (4 << 9));                               \
    half8 q5 = *(const half8*)(wk + (5 << 9));                               \
    half8 q6 = *(const half8*)(wk + (6 << 9));                               \
    half8 q7 = *(const half8*)(wk + (7 << 9));                               \
    MF(q0, bf, acc0); MF(q1, bf, acc1); MF(q2, bf, acc2); MF(q3, bf, acc3);  \
    MF(q4, bd, acc0); MF(q5, bd, acc1); MF(q6, bd, acc2); MF(q7, bd, acc3);  \
} while (0)

// batched pair: issue all 16 gathers for taps K,K+1; process K then K+1
#define TAPPAIR(K) do {                                                      \
    float uA0, uA1, uA2, uA3, uB0, uB1, uB2, uB3;                            \
    float uC0, uC1, uC2, uC3, uD0, uD1, uD2, uD3;                            \
    int iA0, iA1, iA2, iA3, iB0, iB1, iB2, iB3;                              \
    int iC0, iC1, iC2, iC3, iD0, iD1, iD2, iD3;                              \
    MKP(K, pbA, pxg, uA0, uA1, uA2, uA3, iA0, iA1, iA2, iA3);                \
    MKP(K, pbB, 8 + pxg, uB0, uB1, uB2, uB3, iB0, iB1, iB2, iB3);            \
    MKP((K) + 1, pbA, pxg, uC0, uC1, uC2, uC3, iC0, iC1, iC2, iC3);          \
    MKP((K) + 1, pbB, 8 + pxg, uD0, uD1, uD2, uD3, iD0, iD1, iD2, iD3);      \
    half8 a0 = *(const half8*)(xhb + iA0);                                   \
    half8 a1 = *(const half8*)(xhb + iA1);                                   \
    half8 a2 = *(const half8*)(xhb + iA2);                                   \
    half8 a3 = *(const half8*)(xhb + iA3);                                   \
    half8 e0 = *(const half8*)(xhb + iB0);                                   \
    half8 e1 = *(const half8*)(xhb + iB1);                                   \
    half8 e2 = *(const half8*)(xhb + iB2);                                   \
    half8 e3 = *(const half8*)(xhb + iB3);                                   \
    half8 c0 = *(const half8*)(xhb + iC0);                                   \
    half8 c1 = *(const half8*)(xhb + iC1);                                   \
    half8 c2 = *(const half8*)(xhb + iC2);                                   \
    half8 c3 = *(const half8*)(xhb + iC3);                                   \
    half8 f0 = *(const half8*)(xhb + iD0);                                   \
    half8 f1 = *(const half8*)(xhb + iD1);                                   \
    half8 f2 = *(const half8*)(xhb + iD2);                                   \
    half8 f3 = *(const half8*)(xhb + iD3);                                   \
    PROC(K, bb1, a0, a1, a2, a3, e0, e1, e2, e3,                             \
         uA0, uA1, uA2, uA3, uB0, uB1, uB2, uB3);                            \
    PROC((K) + 1, bb2, c0, c1, c2, c3, f0, f1, f2, f3,                       \
         uC0, uC1, uC2, uC3, uD0, uD1, uD2, uD3);                            \
} while (0)

#define TAPSOLO(K) do {                                                      \
    float uA0, uA1, uA2, uA3, uB0, uB1, uB2, uB3;                            \
    int iA0, iA1, iA2, iA3, iB0, iB1, iB2, iB3;                              \
    MKP(K, pbA, pxg, uA0, uA1, uA2, uA3, iA0, iA1, iA2, iA3);                \
    MKP(K, pbB, 8 + pxg, uB0, uB1, uB2, uB3, iB0, iB1, iB2, iB3);            \
    half8 a0 = *(const half8*)(xhb + iA0);                                   \
    half8 a1 = *(const half8*)(xhb + iA1);                                   \
    half8 a2 = *(const half8*)(xhb + iA2);                                   \
    half8 a3 = *(const half8*)(xhb + iA3);                                   \
    half8 e0 = *(const half8*)(xhb + iB0);                                   \
    half8 e1 = *(const half8*)(xhb + iB1);                                   \
    half8 e2 = *(const half8*)(xhb + iB2);                                   \
    half8 e3 = *(const half8*)(xhb + iB3);                                   \
    PROC(K, bb1, a0, a1, a2, a3, e0, e1, e2, e3,                             \
         uA0, uA1, uA2, uA3, uB0, uB1, uB2, uB3);                            \
} while (0)

    TAPPAIR(0);
    TAPPAIR(2);
    TAPPAIR(4);
    TAPPAIR(6);
    TAPSOLO(8);

    // epilogue: D col = pl, row o = m*16 + g*4 + j
    float* outp = out + (size_t)b * OO * HWsz + h * WW + p0 + s * 16 + pl;
#pragma unroll
    for (int j = 0; j < 4; ++j) outp[(size_t)(g * 4 + j) * HWsz] = acc0[j];
#pragma unroll
    for (int j = 0; j < 4; ++j) outp[(size_t)(16 + g * 4 + j) * HWsz] = acc1[j];
#pragma unroll
    for (int j = 0; j < 4; ++j) outp[(size_t)(32 + g * 4 + j) * HWsz] = acc2[j];
#pragma unroll
    for (int j = 0; j < 4; ++j) outp[(size_t)(48 + g * 4 + j) * HWsz] = acc3[j];
}

extern "C" void kernel_launch(void* const* d_in, const int* in_sizes, int n_in,
                              void* d_out, int out_size, void* d_ws, size_t ws_size,
                              hipStream_t stream)
{
    const float* x   = (const float*)d_in[0];
    const float* ow  = (const float*)d_in[1];
    const float* ob  = (const float*)d_in[2];
    const float* mw  = (const float*)d_in[3];
    const float* mb  = (const float*)d_in[4];
    const float* wgt = (const float*)d_in[5];
    float* out = (float*)d_out;

    // ws: xh (4*16384*64 f16 = 8.39MB) | waf (36864 f16) | wcf (18432 f16)
    //                                     ^-- contiguous: staged as one copy
    _Float16* xh  = (_Float16*)d_ws;
    _Float16* waf = xh + (size_t)BB * HWsz * 64;
    _Float16* wcf = waf + 36864;

    pre_kernel<<<dim3(512 + 216), dim3(256), 0, stream>>>(
        x, wgt, ow, mw, xh, waf, wcf);
    fused_kernel<<<dim3(256), dim3(1024), 0, stream>>>(
        waf, xh, ob, mb, out);
}